// Round 9
// baseline (414.079 us; speedup 1.0000x reference)
//
#include <hip/hip_runtime.h>
#include <math.h>
#include <stdint.h>

#define N_BINS 50
#define EDGE_N 51
#define HIST_N 52
#define NTHR 256
#define MAXBLK 1280
#define NREP 16

typedef unsigned int u32;
typedef unsigned short u16;
typedef unsigned char u8;
typedef float f32x4 __attribute__((ext_vector_type(4)));

// ws layout (bytes):
// [0]    u32 minEnc, [4] u32 maxEnc          (reset by k_init each call)
// [8]    int cnt1[16], [72] int cnt2[16]     (barrier counters, zeroed by k_init)
// [256]  int histU[NREP][2*52]
// [6912] int histE[NREP][2*51]
// [16384] u8 codes[n]
// [align16 after codes] float xc[n]

#define KEEP16(v) asm volatile("" :: "v"(v))

__device__ __forceinline__ u32 f32_enc(float f) {
  u32 u = __float_as_uint(f);
  return (u & 0x80000000u) ? ~u : (u | 0x80000000u);
}
__device__ __forceinline__ float f32_dec(u32 k) {
  u32 u = (k & 0x80000000u) ? (k & 0x7fffffffu) : ~k;
  return __uint_as_float(u);
}

// jnp.linspace(xmin, xmax, 51) float32 semantics.
__device__ __forceinline__ float edge_at(int e, float xmin, float xmax) {
  if (e >= N_BINS) return xmax;
  float step = __fdiv_rn((float)e, (float)N_BINS);
  float omst = __fsub_rn(1.0f, step);
  return __fadd_rn(__fmul_rn(xmin, omst), __fmul_rn(xmax, step));
}

__device__ __forceinline__ float bce_f(int c, float n_f, float aC, float bC) {
  float cf = (float)c;  // exact, c < 2^24
  float t = __fadd_rn(__fmul_rn(__fsub_rn(n_f, cf), bC), __fmul_rn(cf, aC));
  return __fdiv_rn(t, n_f);
}

__device__ __forceinline__ void get_ab(float& aC, float& bC) {
  const double epsd = (double)1e-7f;
  aC = (float)(-log1p(-epsd));
  bC = (float)(-log(epsd));
}

// light grid barrier: per-block arrival on 16 split counters (agent scope),
// thread-0-only poll with s_sleep; one threadfence each side (L2 wb/inv per XCD,
// same work a kernel boundary does). Counters zeroed by k_init each call.
__device__ __forceinline__ void gbar(int* cnt, int nblk, int bid) {
  __syncthreads();                 // all block stores drained to L2 (waitcnt before barrier)
  if (threadIdx.x == 0) {
    __threadfence();               // release: write back this XCD's L2
    __hip_atomic_fetch_add(&cnt[bid & (NREP - 1)], 1, __ATOMIC_RELAXED,
                           __HIP_MEMORY_SCOPE_AGENT);
    int s;
    do {
      s = 0;
#pragma unroll
      for (int k = 0; k < NREP; ++k)
        s += __hip_atomic_load(&cnt[k], __ATOMIC_RELAXED, __HIP_MEMORY_SCOPE_AGENT);
      if (s < nblk) __builtin_amdgcn_s_sleep(4);
    } while (s < nblk);
    __threadfence();               // acquire: invalidate L1/L2 so fresh data is fetched
  }
  __syncthreads();
}

__global__ void k_init(u32* __restrict__ wsu, int* __restrict__ histU,
                       int* __restrict__ histE) {
  int t = threadIdx.x;
  if (t == 0) { wsu[0] = 0xFFFFFFFFu; wsu[1] = 0u; }
  if (t < 32) ((int*)(wsu + 2))[t] = 0;  // cnt1[16] + cnt2[16]
  for (int i = t; i < NREP * 2 * HIST_N; i += NTHR) histU[i] = 0;
  for (int i = t; i < NREP * 2 * EDGE_N; i += NTHR) histE[i] = 0;
}

template <int COMPACT>
__global__ void __launch_bounds__(NTHR, 5)
k_all(const f32x4* __restrict__ in4, const int* __restrict__ tgt, int n, int nblk,
      u32* __restrict__ wsu, int* __restrict__ histU, int* __restrict__ histE,
      u8* __restrict__ codes, float* __restrict__ xc, int* __restrict__ out) {
  __shared__ u16 ph[HIST_N][NTHR];     // per-thread private counters, conflict-free
  __shared__ float s_edges[EDGE_N];
  __shared__ int shE[2 * EDGE_N];
  __shared__ float s_red[8];
  __shared__ float s_mm[2];
  __shared__ int s_ns_le[EDGE_N], s_ns_lt[EDGE_N], s_nb_le[EDGE_N], s_nb_lt[EDGE_N];
  __shared__ int s_h0[N_BINS], s_h1[N_BINS];
  __shared__ unsigned char s_g0[N_BINS], s_g1[N_BINS];
  __shared__ unsigned char s_mask[EDGE_N];
  __shared__ float s_rv[NTHR];
  __shared__ int s_ri[NTHR];
  __shared__ int s_cut[3];

  const int tid = threadIdx.x, bid = blockIdx.x;
  const int gid = bid * NTHR + tid;
  const int T = nblk * NTHR;
  int* cnt1 = (int*)(wsu + 2);
  int* cnt2 = (int*)(wsu + 18);

  // ---------------- phase A: minmax + compact ----------------
  float vmin = INFINITY, vmax = -INFINITY;
#pragma unroll 4
  for (int i = gid; i < n; i += T) {
    f32x4 r = in4[i];
    KEEP16(r);
    float x = r.x;
    vmin = fminf(vmin, x);
    vmax = fmaxf(vmax, x);
    if (COMPACT) xc[i] = x;
  }
  // zero LDS hist before the barrier (hides under phase-A drain)
  {
    u32* p32 = (u32*)&ph[0][0];
    for (int i = tid; i < HIST_N * (NTHR / 2); i += NTHR) p32[i] = 0;
    for (int i = tid; i < 2 * EDGE_N; i += NTHR) shE[i] = 0;
  }
  for (int off = 32; off; off >>= 1) {
    vmin = fminf(vmin, __shfl_down(vmin, off));
    vmax = fmaxf(vmax, __shfl_down(vmax, off));
  }
  {
    int wid = tid >> 6;
    if ((tid & 63) == 0) { s_red[wid] = vmin; s_red[4 + wid] = vmax; }
  }
  __syncthreads();
  if (tid == 0) {
    float m = s_red[0], M = s_red[4];
    for (int w = 1; w < NTHR / 64; ++w) { m = fminf(m, s_red[w]); M = fmaxf(M, s_red[4 + w]); }
    atomicMin(&wsu[0], f32_enc(m));
    atomicMax(&wsu[1], f32_enc(M));
  }
  gbar(cnt1, nblk, bid);
  if (tid == 0) {
    s_mm[0] = f32_dec(__hip_atomic_load(&wsu[0], __ATOMIC_RELAXED, __HIP_MEMORY_SCOPE_AGENT));
    s_mm[1] = f32_dec(__hip_atomic_load(&wsu[1], __ATOMIC_RELAXED, __HIP_MEMORY_SCOPE_AGENT));
  }
  __syncthreads();

  // ---------------- phase B: histogram + codes ----------------
  const float xmin = s_mm[0], xmax = s_mm[1];
  if (tid < EDGE_N) s_edges[tid] = edge_at(tid, xmin, xmax);
  __syncthreads();
  {
    const float delta = __fdiv_rn(__fsub_rn(xmax, xmin), (float)N_BINS);
    const float inv_delta = (delta > 0.0f) ? (1.0f / delta) : 0.0f;  // guess only
    const int nv = n >> 2;
    const int base = nv << 2;
    const f32x4* __restrict__ xc4 = (const f32x4*)xc;
    const int4* __restrict__ tgt4 = (const int4*)tgt;
    uchar4* __restrict__ codes4 = (uchar4*)codes;
    for (int iv = gid; iv < nv; iv += T) {
      float xs[4];
      if (COMPACT) {
        f32x4 v = xc4[iv];
        xs[0] = v.x; xs[1] = v.y; xs[2] = v.z; xs[3] = v.w;
      } else {
        f32x4 a = in4[4 * iv + 0], b = in4[4 * iv + 1], c = in4[4 * iv + 2], d = in4[4 * iv + 3];
        xs[0] = a.x; xs[1] = b.x; xs[2] = c.x; xs[3] = d.x;
      }
      int4 tv = tgt4[iv];
      int ts[4] = {tv.x, tv.y, tv.z, tv.w};
      u8 cd[4];
#pragma unroll
      for (int k = 0; k < 4; ++k) {
        float x = xs[k];
        int cls = (ts[k] == 1) ? 0 : 1;
        int g = (int)((x - xmin) * inv_delta);
        g = max(0, min(g, EDGE_N));
        while (g < EDGE_N && s_edges[g] < x) ++g;   // exact: u = #edges < x
        while (g > 0 && s_edges[g - 1] >= x) --g;
        int eq = (g < EDGE_N && s_edges[g] == x) ? 1 : 0;
        ph[g][tid] = (u16)(ph[g][tid] + (1u << (cls * 8)));
        if (eq) atomicAdd(&shE[cls * EDGE_N + g], 1);
        cd[k] = (u8)(g | (eq << 6));
      }
      if (COMPACT) codes4[iv] = make_uchar4(cd[0], cd[1], cd[2], cd[3]);
    }
    if (bid == 0 && tid < (n - base)) {
      int i = base + tid;
      float x = COMPACT ? xc[i] : in4[i].x;
      int cls = (tgt[i] == 1) ? 0 : 1;
      int g = (int)((x - xmin) * inv_delta);
      g = max(0, min(g, EDGE_N));
      while (g < EDGE_N && s_edges[g] < x) ++g;
      while (g > 0 && s_edges[g - 1] >= x) --g;
      int eq = (g < EDGE_N && s_edges[g] == x) ? 1 : 0;
      ph[g][tid] = (u16)(ph[g][tid] + (1u << (cls * 8)));
      if (eq) atomicAdd(&shE[cls * EDGE_N + g], 1);
      if (COMPACT) codes[i] = (u8)(g | (eq << 6));
    }
    __syncthreads();
    int* hU = histU + (bid & (NREP - 1)) * (2 * HIST_N);
    int* hE = histE + (bid & (NREP - 1)) * (2 * EDGE_N);
    if (tid < HIST_N) {  // diagonal stagger over per-thread counters
      const u32* p32 = (const u32*)&ph[0][0];
      u32 c0 = 0, c1 = 0;
      for (int k2 = 0; k2 < NTHR / 2; ++k2) {
        int idx = (k2 + tid) & (NTHR / 2 - 1);
        u32 w = p32[tid * (NTHR / 2) + idx];
        c0 += (w & 0xFFu) + ((w >> 16) & 0xFFu);
        c1 += ((w >> 8) & 0xFFu) + ((w >> 24) & 0xFFu);
      }
      if (c0) atomicAdd(&hU[tid], (int)c0);
      if (c1) atomicAdd(&hU[HIST_N + tid], (int)c1);
    }
    for (int kk = tid; kk < 2 * EDGE_N; kk += NTHR) {
      int v = shE[kk];
      if (v) atomicAdd(&hE[kk], v);
    }
  }
  gbar(cnt2, nblk, bid);

  // ---------------- phase C: decide (redundant per block) + predict ----------------
  if (tid < 128) {
    const int lane = tid & 63;
    const int w = tid >> 6;  // 0: sig, 1: bkg
    int v = 0;
    if (lane < EDGE_N) {
      for (int r = 0; r < NREP; ++r) v += histU[r * (2 * HIST_N) + w * HIST_N + lane];
    }
#pragma unroll
    for (int d = 1; d < 64; d <<= 1) {
      int t = __shfl_up(v, d);
      if (lane >= d) v += t;
    }
    if (lane < EDGE_N) {
      int e = 0;
      for (int r = 0; r < NREP; ++r) e += histE[r * (2 * EDGE_N) + w * EDGE_N + lane];
      if (w == 0) { s_ns_le[lane] = v; s_ns_lt[lane] = v - e; }
      else        { s_nb_le[lane] = v; s_nb_lt[lane] = v - e; }
    }
  }
  if (tid < EDGE_N) s_mask[tid] = 0;
  __syncthreads();
  if (tid < N_BINS) {
    int h0 = s_nb_le[tid + 1] - s_nb_lt[tid];
    int h1 = s_ns_le[tid + 1] - s_ns_lt[tid];
    s_h0[tid] = h0;
    s_h1[tid] = h1;
    s_g0[tid] = h0 > h1;
    s_g1[tid] = h1 > h0;
  }
  __syncthreads();
  if (tid < 64) {
    bool cand = false;
    if (tid + 1 < N_BINS) {
      bool c0 = (s_g0[tid] != s_g0[tid + 1]) && (s_h0[tid] > 0);
      bool c1 = (s_g1[tid] != s_g1[tid + 1]) && (s_h1[tid] > 0);
      cand = c0 || c1;
      if (cand) s_mask[tid + 1] = 1;
    }
    unsigned long long bal = __ballot(cand);
    if (tid == 0 && __popcll(bal) == 1) s_mask[N_BINS] = 1;
  }
  __syncthreads();
  const int Ns = s_ns_le[EDGE_N - 1];
  const int Nb = n - Ns;
  float aC, bC;
  get_ab(aC, bC);
  const float n_f = (float)n;
  float best = INFINITY;
  int bestIdx = 0x7fffffff;
  for (int p = tid; p < EDGE_N * EDGE_N; p += NTHR) {
    int i = p / EDGE_N, j = p - i * EDGE_N;
    float v = INFINITY;
    if (s_mask[i] && s_mask[j] && i < j) {
      int c0 = s_ns_le[i] + (Nb - s_nb_le[i]);
      int c1 = Ns - s_ns_lt[i] + s_nb_lt[i];
      int c2 = s_ns_le[j] - s_ns_lt[i] + Nb - (s_nb_le[j] - s_nb_lt[i]);
      int c3 = s_ns_le[i] + Ns - s_ns_lt[j] + s_nb_le[j] - s_nb_lt[i];
      float L0 = bce_f(c0, n_f, aC, bC);
      float L1 = bce_f(c1, n_f, aC, bC);
      float L2 = bce_f(c2, n_f, aC, bC);
      float L3 = bce_f(c3, n_f, aC, bC);
      v = L0;
      if (L1 < v) v = L1;
      if (L2 < v) v = L2;
      if (L3 < v) v = L3;
    }
    if (v < best || (v == best && p < bestIdx)) { best = v; bestIdx = p; }
  }
  s_rv[tid] = best;
  s_ri[tid] = bestIdx;
  __syncthreads();
  for (int s = NTHR / 2; s > 0; s >>= 1) {
    if (tid < s) {
      float ov = s_rv[tid + s];
      int oi = s_ri[tid + s];
      if (ov < s_rv[tid] || (ov == s_rv[tid] && oi < s_ri[tid])) {
        s_rv[tid] = ov;
        s_ri[tid] = oi;
      }
    }
    __syncthreads();
  }
  if (tid == 0) {
    int p = s_ri[0];
    int i = p / EDGE_N, j = p - i * EDGE_N;
    int c0 = s_ns_le[i] + (Nb - s_nb_le[i]);
    int c1 = Ns - s_ns_lt[i] + s_nb_lt[i];
    int c2 = s_ns_le[j] - s_ns_lt[i] + Nb - (s_nb_le[j] - s_nb_lt[i]);
    int c3 = s_ns_le[i] + Ns - s_ns_lt[j] + s_nb_le[j] - s_nb_lt[i];
    float L0 = bce_f(c0, n_f, aC, bC);
    float L1 = bce_f(c1, n_f, aC, bC);
    float L2 = bce_f(c2, n_f, aC, bC);
    float L3 = bce_f(c3, n_f, aC, bC);
    int cs = 0;
    float m = L0;
    if (L1 < m) { m = L1; cs = 1; }
    if (L2 < m) { m = L2; cs = 2; }
    if (L3 < m) { m = L3; cs = 3; }
    s_cut[0] = cs;
    s_cut[1] = i;
    s_cut[2] = j;
  }
  __syncthreads();

  const int cs = s_cut[0], ci = s_cut[1], cj = s_cut[2];
  if (COMPACT) {
    const uchar4* __restrict__ c4 = (const uchar4*)codes;
    int4* __restrict__ out4 = (int4*)out;
    const int nv = n >> 2;
    for (int iv = gid; iv < nv; iv += T) {
      uchar4 c = c4[iv];
      u8 bys[4] = {c.x, c.y, c.z, c.w};
      int r[4];
#pragma unroll
      for (int b = 0; b < 4; ++b) {
        int u = (int)(bys[b] & 63u);
        int v = u + (int)(bys[b] >> 6);
        bool p0 = (u <= ci), p1 = (ci < v);
        bool p = (cs == 0) ? p0 : (cs == 1) ? p1 : (cs == 2) ? (p1 && (u <= cj)) : (p0 || (cj < v));
        r[b] = p ? 1 : 0;
      }
      out4[iv] = make_int4(r[0], r[1], r[2], r[3]);
    }
    const int cbase = (n >> 2) << 2;
    if (bid == 0 && tid < (n - cbase)) {
      int i = cbase + tid;
      u32 by = codes[i];
      int u = (int)(by & 63u);
      int v = u + (int)(by >> 6);
      bool p0 = (u <= ci), p1 = (ci < v);
      bool p = (cs == 0) ? p0 : (cs == 1) ? p1 : (cs == 2) ? (p1 && (u <= cj)) : (p0 || (cj < v));
      out[i] = p ? 1 : 0;
    }
  } else {
    const float lower = edge_at(ci, xmin, xmax);
    const float upper = edge_at(cj, xmin, xmax);
    for (int i = gid; i < n; i += T) {
      f32x4 r = in4[i];
      float x = r.x;
      bool p;
      if (cs == 0) p = (x <= lower);
      else if (cs == 1) p = (x >= lower);
      else if (cs == 2) p = (x >= lower) && (x <= upper);
      else p = (x <= lower) || (x >= upper);
      out[i] = p ? 1 : 0;
    }
  }
}

extern "C" void kernel_launch(void* const* d_in, const int* in_sizes, int n_in,
                              void* d_out, int out_size, void* d_ws, size_t ws_size,
                              hipStream_t stream) {
  const f32x4* in4 = (const f32x4*)d_in[0];
  const int* tgt = (const int*)d_in[1];
  int n = in_sizes[1];
  int* out = (int*)d_out;
  char* ws = (char*)d_ws;
  u32* wsu = (u32*)ws;
  int* histU = (int*)(ws + 256);
  int* histE = (int*)(ws + 256 + NREP * 2 * HIST_N * 4);
  u8* codes = (u8*)(ws + 16384);
  size_t xcOff = ((size_t)16384 + (size_t)n + 15) & ~(size_t)15;
  float* xc = (float*)(ws + xcOff);
  const bool compact = ws_size >= xcOff + (size_t)n * 4u;

  // co-resident grid size (deterministic across calls); fallback conservative.
  int maxb = 0;
  hipError_t oe = hipOccupancyMaxActiveBlocksPerMultiprocessor(
      &maxb, compact ? (const void*)k_all<1> : (const void*)k_all<0>, NTHR, 0);
  int nblk = MAXBLK;
  if (oe == hipSuccess && maxb > 0) {
    int cap = maxb * 256;  // 256 CUs on gfx950
    if (cap < nblk) nblk = cap;
  } else {
    nblk = 1024;
  }

  k_init<<<1, NTHR, 0, stream>>>(wsu, histU, histE);
  if (compact) {
    void* args[10] = {(void*)&in4, (void*)&tgt, (void*)&n, (void*)&nblk, (void*)&wsu,
                      (void*)&histU, (void*)&histE, (void*)&codes, (void*)&xc, (void*)&out};
    hipLaunchCooperativeKernel((void*)k_all<1>, dim3(nblk), dim3(NTHR), args, 0, stream);
  } else {
    void* args[10] = {(void*)&in4, (void*)&tgt, (void*)&n, (void*)&nblk, (void*)&wsu,
                      (void*)&histU, (void*)&histE, (void*)&codes, (void*)&xc, (void*)&out};
    hipLaunchCooperativeKernel((void*)k_all<0>, dim3(nblk), dim3(NTHR), args, 0, stream);
  }
}

// Round 10
// 210.021 us; speedup vs baseline: 1.9716x; 1.9716x over previous
//
#include <hip/hip_runtime.h>
#include <math.h>
#include <stdint.h>

#define N_BINS 50
#define EDGE_N 51
#define HIST_N 52
#define NTHR 256
#define MAXBLK 1280
#define NREP 16

typedef unsigned int u32;
typedef unsigned short u16;
typedef unsigned char u8;
typedef float f32x4 __attribute__((ext_vector_type(4)));

// ws layout (bytes):
// [0]  u32 minEnc  [4] u32 maxEnc
// [8]  u32 cnt1    [12] u32 flag1   [16] u32 cnt2   [20] u32 cutflag
// [256]   int histU[NREP][2*52]
// [6912]  int histE[NREP][2*51]
// [16384] u8 codes[n]           (u | eq<<6; written & read by SAME thread index)
// [align16 after codes] float xc[n]  (written & read by SAME thread index)
//
// Cross-block data flows ONLY through device/agent atomics (coherence point).
// xc/codes are same-thread self-communication -> local L2, no fences needed.

#define KEEP16(v) asm volatile("" :: "v"(v))

#define ALOAD(p)     __hip_atomic_load((p), __ATOMIC_RELAXED, __HIP_MEMORY_SCOPE_AGENT)
#define ASTORE(p, v) __hip_atomic_store((p), (v), __ATOMIC_RELAXED, __HIP_MEMORY_SCOPE_AGENT)
#define AADD(p, v)   __hip_atomic_fetch_add((p), (v), __ATOMIC_RELAXED, __HIP_MEMORY_SCOPE_AGENT)

__device__ __forceinline__ u32 f32_enc(float f) {
  u32 u = __float_as_uint(f);
  return (u & 0x80000000u) ? ~u : (u | 0x80000000u);
}
__device__ __forceinline__ float f32_dec(u32 k) {
  u32 u = (k & 0x80000000u) ? (k & 0x7fffffffu) : ~k;
  return __uint_as_float(u);
}

// jnp.linspace(xmin, xmax, 51) float32 semantics.
__device__ __forceinline__ float edge_at(int e, float xmin, float xmax) {
  if (e >= N_BINS) return xmax;
  float step = __fdiv_rn((float)e, (float)N_BINS);
  float omst = __fsub_rn(1.0f, step);
  return __fadd_rn(__fmul_rn(xmin, omst), __fmul_rn(xmax, step));
}

__device__ __forceinline__ float bce_f(int c, float n_f, float aC, float bC) {
  float cf = (float)c;  // exact, c < 2^24
  float t = __fadd_rn(__fmul_rn(__fsub_rn(n_f, cf), bC), __fmul_rn(cf, aC));
  return __fdiv_rn(t, n_f);
}

__device__ __forceinline__ void get_ab(float& aC, float& bC) {
  const double epsd = (double)1e-7f;
  aC = (float)(-log1p(-epsd));
  bC = (float)(-log(epsd));
}

__global__ void k_init(u32* __restrict__ wsu, int* __restrict__ histU,
                       int* __restrict__ histE) {
  int t = threadIdx.x;
  if (t == 0) {
    wsu[0] = 0xFFFFFFFFu;  // minEnc
    wsu[1] = 0u;           // maxEnc
    wsu[2] = 0u;           // cnt1
    wsu[3] = 0u;           // flag1
    wsu[4] = 0u;           // cnt2
    wsu[5] = 0u;           // cutflag
  }
  for (int i = t; i < NREP * 2 * HIST_N; i += NTHR) histU[i] = 0;
  for (int i = t; i < NREP * 2 * EDGE_N; i += NTHR) histE[i] = 0;
}

template <int COMPACT>
__global__ void __launch_bounds__(NTHR, 5)
k_all(const f32x4* __restrict__ in4, const int* __restrict__ tgt, int n, int nblk,
      u32* __restrict__ wsu, int* __restrict__ histU, int* __restrict__ histE,
      u8* __restrict__ codes, float* __restrict__ xc, int* __restrict__ out) {
  __shared__ u16 ph[HIST_N][NTHR];  // per-thread private counters, bank-conflict-free
  __shared__ float s_edges[EDGE_N];
  __shared__ int shE[2 * EDGE_N];
  __shared__ float s_red[8];
  __shared__ float s_mm[2];
  __shared__ int s_ns_le[EDGE_N], s_ns_lt[EDGE_N], s_nb_le[EDGE_N], s_nb_lt[EDGE_N];
  __shared__ int s_h0[N_BINS], s_h1[N_BINS];
  __shared__ unsigned char s_g0[N_BINS], s_g1[N_BINS];
  __shared__ unsigned char s_mask[EDGE_N];
  __shared__ float s_rv[NTHR];
  __shared__ int s_ri[NTHR];
  __shared__ int s_cut[3];

  const int tid = threadIdx.x, bid = blockIdx.x;
  const int gid = bid * NTHR + tid;
  const int T = nblk * NTHR;
  u32* cnt1 = &wsu[2];
  u32* flag1 = &wsu[3];
  u32* cnt2 = &wsu[4];
  u32* cutflag = &wsu[5];

  // zero LDS hist state (block-local; any point before phase B works)
  {
    u32* p32 = (u32*)&ph[0][0];
    for (int i = tid; i < HIST_N * (NTHR / 2); i += NTHR) p32[i] = 0;
    for (int i = tid; i < 2 * EDGE_N; i += NTHR) shE[i] = 0;
  }

  // ---------------- phase A: minmax + compact (same-index scalar layout) ----------
  float vmin = INFINITY, vmax = -INFINITY;
  for (int i = gid; i < n; i += T) {
    f32x4 r = in4[i];          // 16 B/lane contiguous row load
    KEEP16(r);
    float x = r.x;
    vmin = fminf(vmin, x);
    vmax = fmaxf(vmax, x);
    if (COMPACT) xc[i] = x;    // 4 B/lane contiguous; re-read by SAME thread in B
  }
  for (int off = 32; off; off >>= 1) {
    vmin = fminf(vmin, __shfl_down(vmin, off));
    vmax = fmaxf(vmax, __shfl_down(vmax, off));
  }
  {
    int wid = tid >> 6;
    if ((tid & 63) == 0) { s_red[wid] = vmin; s_red[4 + wid] = vmax; }
  }
  __syncthreads();
  if (tid == 0) {
    float m = s_red[0], M = s_red[4];
    for (int w = 1; w < NTHR / 64; ++w) { m = fminf(m, s_red[w]); M = fmaxf(M, s_red[4 + w]); }
    atomicMin(&wsu[0], f32_enc(m));   // device atomics: coherent across XCDs
    atomicMax(&wsu[1], f32_enc(M));
  }
  // ---- barrier 1 (fence-free): syncthreads drained vmcnt -> atomics ack'd ----
  __syncthreads();
  if (tid == 0) {
    u32 prev = AADD(cnt1, 1u);
    if (prev == (u32)(nblk - 1)) {
      ASTORE(flag1, 1u);
    } else {
      while (ALOAD(flag1) == 0u) __builtin_amdgcn_s_sleep(16);
    }
    s_mm[0] = f32_dec(ALOAD(&wsu[0]));
    s_mm[1] = f32_dec(ALOAD(&wsu[1]));
  }
  __syncthreads();

  // ---------------- phase B: histogram + codes ----------------
  const float xmin = s_mm[0], xmax = s_mm[1];
  if (tid < EDGE_N) s_edges[tid] = edge_at(tid, xmin, xmax);
  __syncthreads();
  {
    const float delta = __fdiv_rn(__fsub_rn(xmax, xmin), (float)N_BINS);
    const float inv_delta = (delta > 0.0f) ? (1.0f / delta) : 0.0f;  // guess only
    for (int i = gid; i < n; i += T) {
      float x;
      if (COMPACT) x = xc[i];          // self-written, local-L2 hot
      else { f32x4 r = in4[i]; KEEP16(r); x = r.x; }
      int cls = (tgt[i] == 1) ? 0 : 1;
      int g = (int)((x - xmin) * inv_delta);
      g = max(0, min(g, EDGE_N));
      while (g < EDGE_N && s_edges[g] < x) ++g;   // exact: u = #edges < x
      while (g > 0 && s_edges[g - 1] >= x) --g;
      int eq = (g < EDGE_N && s_edges[g] == x) ? 1 : 0;
      ph[g][tid] = (u16)(ph[g][tid] + (1u << (cls * 8)));
      if (eq) atomicAdd(&shE[cls * EDGE_N + g], 1);
      if (COMPACT) codes[i] = (u8)(g | (eq << 6));  // self-read in phase D
    }
    __syncthreads();
    int* hU = histU + (bid & (NREP - 1)) * (2 * HIST_N);
    int* hE = histE + (bid & (NREP - 1)) * (2 * EDGE_N);
    if (tid < HIST_N) {  // diagonal stagger over per-thread counters
      const u32* p32 = (const u32*)&ph[0][0];
      u32 c0 = 0, c1 = 0;
      for (int k2 = 0; k2 < NTHR / 2; ++k2) {
        int idx = (k2 + tid) & (NTHR / 2 - 1);
        u32 w = p32[tid * (NTHR / 2) + idx];
        c0 += (w & 0xFFu) + ((w >> 16) & 0xFFu);
        c1 += ((w >> 8) & 0xFFu) + ((w >> 24) & 0xFFu);
      }
      if (c0) atomicAdd(&hU[tid], (int)c0);
      if (c1) atomicAdd(&hU[HIST_N + tid], (int)c1);
    }
    for (int kk = tid; kk < 2 * EDGE_N; kk += NTHR) {
      int v = shE[kk];
      if (v) atomicAdd(&hE[kk], v);
    }
  }
  // ---- barrier 2 + decide by block 0 only; others poll the packed cut ----
  __syncthreads();  // drains this block's hist atomics
  if (bid == 0) {
    if (tid == 0) {
      AADD(cnt2, 1u);
      while (ALOAD(cnt2) < (u32)nblk) __builtin_amdgcn_s_sleep(16);
    }
    __syncthreads();
    // ---- decide (verified math; hist reads via relaxed atomic loads) ----
    if (tid < 128) {
      const int lane = tid & 63;
      const int w = tid >> 6;  // 0: sig, 1: bkg
      int v = 0;
      if (lane < EDGE_N) {
        for (int r = 0; r < NREP; ++r)
          v += ALOAD(&histU[r * (2 * HIST_N) + w * HIST_N + lane]);
      }
#pragma unroll
      for (int d = 1; d < 64; d <<= 1) {
        int t = __shfl_up(v, d);
        if (lane >= d) v += t;
      }
      if (lane < EDGE_N) {
        int e = 0;
        for (int r = 0; r < NREP; ++r)
          e += ALOAD(&histE[r * (2 * EDGE_N) + w * EDGE_N + lane]);
        if (w == 0) { s_ns_le[lane] = v; s_ns_lt[lane] = v - e; }
        else        { s_nb_le[lane] = v; s_nb_lt[lane] = v - e; }
      }
    }
    if (tid < EDGE_N) s_mask[tid] = 0;
    __syncthreads();
    if (tid < N_BINS) {
      int h0 = s_nb_le[tid + 1] - s_nb_lt[tid];
      int h1 = s_ns_le[tid + 1] - s_ns_lt[tid];
      s_h0[tid] = h0;
      s_h1[tid] = h1;
      s_g0[tid] = h0 > h1;
      s_g1[tid] = h1 > h0;
    }
    __syncthreads();
    if (tid < 64) {
      bool cand = false;
      if (tid + 1 < N_BINS) {
        bool c0 = (s_g0[tid] != s_g0[tid + 1]) && (s_h0[tid] > 0);
        bool c1 = (s_g1[tid] != s_g1[tid + 1]) && (s_h1[tid] > 0);
        cand = c0 || c1;
        if (cand) s_mask[tid + 1] = 1;
      }
      unsigned long long bal = __ballot(cand);
      if (tid == 0 && __popcll(bal) == 1) s_mask[N_BINS] = 1;
    }
    __syncthreads();
    const int Ns = s_ns_le[EDGE_N - 1];
    const int Nb = n - Ns;
    float aC, bC;
    get_ab(aC, bC);
    const float n_f = (float)n;
    float best = INFINITY;
    int bestIdx = 0x7fffffff;
    for (int p = tid; p < EDGE_N * EDGE_N; p += NTHR) {
      int i = p / EDGE_N, j = p - i * EDGE_N;
      float v = INFINITY;
      if (s_mask[i] && s_mask[j] && i < j) {
        int c0 = s_ns_le[i] + (Nb - s_nb_le[i]);
        int c1 = Ns - s_ns_lt[i] + s_nb_lt[i];
        int c2 = s_ns_le[j] - s_ns_lt[i] + Nb - (s_nb_le[j] - s_nb_lt[i]);
        int c3 = s_ns_le[i] + Ns - s_ns_lt[j] + s_nb_le[j] - s_nb_lt[i];
        float L0 = bce_f(c0, n_f, aC, bC);
        float L1 = bce_f(c1, n_f, aC, bC);
        float L2 = bce_f(c2, n_f, aC, bC);
        float L3 = bce_f(c3, n_f, aC, bC);
        v = L0;
        if (L1 < v) v = L1;
        if (L2 < v) v = L2;
        if (L3 < v) v = L3;
      }
      if (v < best || (v == best && p < bestIdx)) { best = v; bestIdx = p; }
    }
    s_rv[tid] = best;
    s_ri[tid] = bestIdx;
    __syncthreads();
    for (int s = NTHR / 2; s > 0; s >>= 1) {
      if (tid < s) {
        float ov = s_rv[tid + s];
        int oi = s_ri[tid + s];
        if (ov < s_rv[tid] || (ov == s_rv[tid] && oi < s_ri[tid])) {
          s_rv[tid] = ov;
          s_ri[tid] = oi;
        }
      }
      __syncthreads();
    }
    if (tid == 0) {
      int p = s_ri[0];
      int i = p / EDGE_N, j = p - i * EDGE_N;
      int c0 = s_ns_le[i] + (Nb - s_nb_le[i]);
      int c1 = Ns - s_ns_lt[i] + s_nb_lt[i];
      int c2 = s_ns_le[j] - s_ns_lt[i] + Nb - (s_nb_le[j] - s_nb_lt[i]);
      int c3 = s_ns_le[i] + Ns - s_ns_lt[j] + s_nb_le[j] - s_nb_lt[i];
      float L0 = bce_f(c0, n_f, aC, bC);
      float L1 = bce_f(c1, n_f, aC, bC);
      float L2 = bce_f(c2, n_f, aC, bC);
      float L3 = bce_f(c3, n_f, aC, bC);
      int cs = 0;
      float m = L0;
      if (L1 < m) { m = L1; cs = 1; }
      if (L2 < m) { m = L2; cs = 2; }
      if (L3 < m) { m = L3; cs = 3; }
      s_cut[0] = cs;
      s_cut[1] = i;
      s_cut[2] = j;
      ASTORE(cutflag, 0x80000000u | ((u32)cs << 16) | ((u32)i << 8) | (u32)j);
    }
    __syncthreads();
  } else {
    if (tid == 0) {
      AADD(cnt2, 1u);
      u32 f;
      while ((f = ALOAD(cutflag)) == 0u) __builtin_amdgcn_s_sleep(32);
      s_cut[0] = (int)((f >> 16) & 3u);
      s_cut[1] = (int)((f >> 8) & 63u);
      s_cut[2] = (int)(f & 63u);
    }
    __syncthreads();
  }

  // ---------------- phase D: predict (same-index scalar layout) ----------------
  const int cs = s_cut[0], ci = s_cut[1], cj = s_cut[2];
  if (COMPACT) {
    for (int i = gid; i < n; i += T) {
      u32 by = codes[i];               // self-written, local-L2 hot
      int u = (int)(by & 63u);
      int v = u + (int)(by >> 6);
      bool p0 = (u <= ci), p1 = (ci < v);
      bool p = (cs == 0) ? p0 : (cs == 1) ? p1 : (cs == 2) ? (p1 && (u <= cj)) : (p0 || (cj < v));
      out[i] = p ? 1 : 0;
    }
  } else {
    const float lower = edge_at(ci, xmin, xmax);
    const float upper = edge_at(cj, xmin, xmax);
    for (int i = gid; i < n; i += T) {
      f32x4 r = in4[i];
      KEEP16(r);
      float x = r.x;
      bool p;
      if (cs == 0) p = (x <= lower);
      else if (cs == 1) p = (x >= lower);
      else if (cs == 2) p = (x >= lower) && (x <= upper);
      else p = (x <= lower) || (x >= upper);
      out[i] = p ? 1 : 0;
    }
  }
}

extern "C" void kernel_launch(void* const* d_in, const int* in_sizes, int n_in,
                              void* d_out, int out_size, void* d_ws, size_t ws_size,
                              hipStream_t stream) {
  const f32x4* in4 = (const f32x4*)d_in[0];
  const int* tgt = (const int*)d_in[1];
  int n = in_sizes[1];
  int* out = (int*)d_out;
  char* ws = (char*)d_ws;
  u32* wsu = (u32*)ws;
  int* histU = (int*)(ws + 256);
  int* histE = (int*)(ws + 6912);
  u8* codes = (u8*)(ws + 16384);
  size_t xcOff = ((size_t)16384 + (size_t)n + 15) & ~(size_t)15;
  float* xc = (float*)(ws + xcOff);
  const bool compact = ws_size >= xcOff + (size_t)n * 4u;

  int maxb = 0;
  hipError_t oe = hipOccupancyMaxActiveBlocksPerMultiprocessor(
      &maxb, compact ? (const void*)k_all<1> : (const void*)k_all<0>, NTHR, 0);
  int nblk = MAXBLK;
  if (oe == hipSuccess && maxb > 0) {
    int cap = maxb * 256;  // 256 CUs on gfx950
    if (cap < nblk) nblk = cap;
  } else {
    nblk = 1024;
  }

  k_init<<<1, NTHR, 0, stream>>>(wsu, histU, histE);
  void* args[10] = {(void*)&in4, (void*)&tgt, (void*)&n, (void*)&nblk, (void*)&wsu,
                    (void*)&histU, (void*)&histE, (void*)&codes, (void*)&xc, (void*)&out};
  if (compact) {
    hipLaunchCooperativeKernel((void*)k_all<1>, dim3(nblk), dim3(NTHR), args, 0, stream);
  } else {
    hipLaunchCooperativeKernel((void*)k_all<0>, dim3(nblk), dim3(NTHR), args, 0, stream);
  }
}

// Round 11
// 137.504 us; speedup vs baseline: 3.0114x; 1.5274x over previous
//
#include <hip/hip_runtime.h>
#include <math.h>
#include <stdint.h>

#define N_BINS 50
#define EDGE_N 51
#define HIST_N 52
#define NTHR 256
#define MAXBLK 1280
#define NREP 16

typedef unsigned int u32;
typedef unsigned short u16;
typedef unsigned char u8;
typedef float f32x4 __attribute__((ext_vector_type(4)));

// ws layout (bytes). All polled words replicated 16x at 64B stride (distinct LLC lines).
// [0] minEnc  [4] maxEnc
// [64   + i*64] cnt1[i]     (barrier-1 arrivals, i<16)
// [1088 + i*64] flag1[i]    (barrier-1 release flags)
// [2112 + i*64] pubMin[i]
// [3136 + i*64] pubMax[i]
// [4160 + i*64] cnt2[i]     (barrier-2 arrivals)
// [5184 + i*64] pub2[i]     (packed cut, bit31 = valid)
// [8192]  int histU[NREP][2*52]
// [14848] int histE[NREP][2*51]
// [24576] u8 codes[n]            (self-written/self-read per thread)
// [align16 after codes] float xc[n]  (self-written/self-read per thread)

#define KEEP16(v) asm volatile("" :: "v"(v))
#define ALOAD(p)     __hip_atomic_load((p), __ATOMIC_RELAXED, __HIP_MEMORY_SCOPE_AGENT)
#define ASTORE(p, v) __hip_atomic_store((p), (v), __ATOMIC_RELAXED, __HIP_MEMORY_SCOPE_AGENT)
#define AADD(p, v)   __hip_atomic_fetch_add((p), (v), __ATOMIC_RELAXED, __HIP_MEMORY_SCOPE_AGENT)
#define VDRAIN() asm volatile("s_waitcnt vmcnt(0)" ::: "memory")

__device__ __forceinline__ u32 f32_enc(float f) {
  u32 u = __float_as_uint(f);
  return (u & 0x80000000u) ? ~u : (u | 0x80000000u);
}
__device__ __forceinline__ float f32_dec(u32 k) {
  u32 u = (k & 0x80000000u) ? (k & 0x7fffffffu) : ~k;
  return __uint_as_float(u);
}
__device__ __forceinline__ u32* slot(u32* wsu, int base_b, int i) {
  return (u32*)((char*)wsu + base_b + i * 64);
}

// jnp.linspace(xmin, xmax, 51) float32 semantics.
__device__ __forceinline__ float edge_at(int e, float xmin, float xmax) {
  if (e >= N_BINS) return xmax;
  float step = __fdiv_rn((float)e, (float)N_BINS);
  float omst = __fsub_rn(1.0f, step);
  return __fadd_rn(__fmul_rn(xmin, omst), __fmul_rn(xmax, step));
}

__device__ __forceinline__ float bce_f(int c, float n_f, float aC, float bC) {
  float cf = (float)c;  // exact, c < 2^24
  float t = __fadd_rn(__fmul_rn(__fsub_rn(n_f, cf), bC), __fmul_rn(cf, aC));
  return __fdiv_rn(t, n_f);
}

__device__ __forceinline__ void get_ab(float& aC, float& bC) {
  const double epsd = (double)1e-7f;
  aC = (float)(-log1p(-epsd));
  bC = (float)(-log(epsd));
}

__global__ void k_init(u32* __restrict__ wsu) {
  // zero control block [0, 8192) and hists [8192, 21376)
  const int t = threadIdx.x;
  if (t == 0) { wsu[0] = 0xFFFFFFFFu; wsu[1] = 0u; }
  for (int i = 2 + t; i < 21376 / 4; i += NTHR) wsu[i] = 0u;
}

template <int COMPACT>
__global__ void __launch_bounds__(NTHR, 5)
k_all(const f32x4* __restrict__ in4, const int* __restrict__ tgt, int n, int nblk,
      u32* __restrict__ wsu, int* __restrict__ histU, int* __restrict__ histE,
      u8* __restrict__ codes, float* __restrict__ xc, int* __restrict__ out) {
  __shared__ u16 ph[HIST_N][NTHR];  // per-thread private counters, bank-conflict-free
  __shared__ float s_edges[EDGE_N];
  __shared__ int shE[2 * EDGE_N];
  __shared__ float s_red[8];
  __shared__ float s_mm[2];
  __shared__ int s_ns_le[EDGE_N], s_ns_lt[EDGE_N], s_nb_le[EDGE_N], s_nb_lt[EDGE_N];
  __shared__ int s_h0[N_BINS], s_h1[N_BINS];
  __shared__ unsigned char s_g0[N_BINS], s_g1[N_BINS];
  __shared__ unsigned char s_mask[EDGE_N];
  __shared__ float s_rv[NTHR];
  __shared__ int s_ri[NTHR];
  __shared__ int s_cut[3];

  const int tid = threadIdx.x, bid = blockIdx.x;
  const int gid = bid * NTHR + tid;
  const int T = nblk * NTHR;
  const int rep = bid & (NREP - 1);

  // zero LDS hist state
  {
    u32* p32 = (u32*)&ph[0][0];
    for (int i = tid; i < HIST_N * (NTHR / 2); i += NTHR) p32[i] = 0;
    for (int i = tid; i < 2 * EDGE_N; i += NTHR) shE[i] = 0;
  }

  // ---------------- phase A: minmax + compact ----------------
  float vmin = INFINITY, vmax = -INFINITY;
  for (int i = gid; i < n; i += T) {
    f32x4 r = in4[i];  // 16 B/lane contiguous row load
    KEEP16(r);
    float x = r.x;
    vmin = fminf(vmin, x);
    vmax = fmaxf(vmax, x);
    if (COMPACT) xc[i] = x;  // self-read in phase B (same thread, same CU)
  }
  for (int off = 32; off; off >>= 1) {
    vmin = fminf(vmin, __shfl_down(vmin, off));
    vmax = fmaxf(vmax, __shfl_down(vmax, off));
  }
  {
    int wid = tid >> 6;
    if ((tid & 63) == 0) { s_red[wid] = vmin; s_red[4 + wid] = vmax; }
  }
  __syncthreads();
  if (tid == 0) {
    float m = s_red[0], M = s_red[4];
    for (int w = 1; w < NTHR / 64; ++w) { m = fminf(m, s_red[w]); M = fmaxf(M, s_red[4 + w]); }
    atomicMin(&wsu[0], f32_enc(m));
    atomicMax(&wsu[1], f32_enc(M));
  }
  __syncthreads();
  // ---- barrier 1: replicated arrivals, block-0 collector, replicated release ----
  if (tid == 0) {
    VDRAIN();  // min/max atomics committed at LLC before arrival
    AADD(slot(wsu, 64, rep), 1u);
    if (bid == 0) {
      u32 s;
      do {
        s = 0;
#pragma unroll
        for (int k = 0; k < NREP; ++k) s += ALOAD(slot(wsu, 64, k));
        if (s < (u32)nblk) __builtin_amdgcn_s_sleep(8);
      } while (s < (u32)nblk);
      u32 mn = ALOAD(&wsu[0]);
      u32 mx = ALOAD(&wsu[1]);
#pragma unroll
      for (int k = 0; k < NREP; ++k) {
        ASTORE(slot(wsu, 2112, k), mn);
        ASTORE(slot(wsu, 3136, k), mx);
      }
      VDRAIN();  // pub committed before flags
#pragma unroll
      for (int k = 0; k < NREP; ++k) ASTORE(slot(wsu, 1088, k), 1u);
      s_mm[0] = f32_dec(mn);
      s_mm[1] = f32_dec(mx);
    } else {
      while (ALOAD(slot(wsu, 1088, rep)) == 0u) __builtin_amdgcn_s_sleep(127);
      s_mm[0] = f32_dec(ALOAD(slot(wsu, 2112, rep)));
      s_mm[1] = f32_dec(ALOAD(slot(wsu, 3136, rep)));
    }
  }
  __syncthreads();

  // ---------------- phase B: histogram + codes ----------------
  const float xmin = s_mm[0], xmax = s_mm[1];
  if (tid < EDGE_N) s_edges[tid] = edge_at(tid, xmin, xmax);
  __syncthreads();
  {
    const float delta = __fdiv_rn(__fsub_rn(xmax, xmin), (float)N_BINS);
    const float inv_delta = (delta > 0.0f) ? (1.0f / delta) : 0.0f;  // guess only
    for (int i = gid; i < n; i += T) {
      float x;
      if (COMPACT) x = xc[i];
      else { f32x4 r = in4[i]; KEEP16(r); x = r.x; }
      int cls = (tgt[i] == 1) ? 0 : 1;
      int g = (int)((x - xmin) * inv_delta);
      g = max(0, min(g, EDGE_N));
      while (g < EDGE_N && s_edges[g] < x) ++g;   // exact: u = #edges < x
      while (g > 0 && s_edges[g - 1] >= x) --g;
      int eq = (g < EDGE_N && s_edges[g] == x) ? 1 : 0;
      ph[g][tid] = (u16)(ph[g][tid] + (1u << (cls * 8)));
      if (eq) atomicAdd(&shE[cls * EDGE_N + g], 1);
      if (COMPACT) codes[i] = (u8)(g | (eq << 6));  // self-read in phase D
    }
    __syncthreads();
    int* hU = histU + rep * (2 * HIST_N);
    int* hE = histE + rep * (2 * EDGE_N);
    if (tid < HIST_N) {  // diagonal stagger over per-thread counters
      const u32* p32 = (const u32*)&ph[0][0];
      u32 c0 = 0, c1 = 0;
      for (int k2 = 0; k2 < NTHR / 2; ++k2) {
        int idx = (k2 + tid) & (NTHR / 2 - 1);
        u32 w = p32[tid * (NTHR / 2) + idx];
        c0 += (w & 0xFFu) + ((w >> 16) & 0xFFu);
        c1 += ((w >> 8) & 0xFFu) + ((w >> 24) & 0xFFu);
      }
      if (c0) atomicAdd(&hU[tid], (int)c0);
      if (c1) atomicAdd(&hU[HIST_N + tid], (int)c1);
    }
    for (int kk = tid; kk < 2 * EDGE_N; kk += NTHR) {
      int v = shE[kk];
      if (v) atomicAdd(&hE[kk], v);
    }
  }
  __syncthreads();
  // ---- barrier 2: arrivals; block 0 decides; packed cut released replicated ----
  if (tid == 0) {
    VDRAIN();  // hist atomics committed before arrival
    AADD(slot(wsu, 4160, rep), 1u);
  }
  if (bid == 0) {
    if (tid == 0) {
      u32 s;
      do {
        s = 0;
#pragma unroll
        for (int k = 0; k < NREP; ++k) s += ALOAD(slot(wsu, 4160, k));
        if (s < (u32)nblk) __builtin_amdgcn_s_sleep(8);
      } while (s < (u32)nblk);
    }
    __syncthreads();
    // ---- decide (verified math; hist reads via atomic loads) ----
    if (tid < 128) {
      const int lane = tid & 63;
      const int w = tid >> 6;  // 0: sig, 1: bkg
      int v = 0;
      if (lane < EDGE_N) {
        for (int r = 0; r < NREP; ++r)
          v += ALOAD((u32*)&histU[r * (2 * HIST_N) + w * HIST_N + lane]);
      }
#pragma unroll
      for (int d = 1; d < 64; d <<= 1) {
        int t = __shfl_up(v, d);
        if (lane >= d) v += t;
      }
      if (lane < EDGE_N) {
        int e = 0;
        for (int r = 0; r < NREP; ++r)
          e += ALOAD((u32*)&histE[r * (2 * EDGE_N) + w * EDGE_N + lane]);
        if (w == 0) { s_ns_le[lane] = v; s_ns_lt[lane] = v - e; }
        else        { s_nb_le[lane] = v; s_nb_lt[lane] = v - e; }
      }
    }
    if (tid < EDGE_N) s_mask[tid] = 0;
    __syncthreads();
    if (tid < N_BINS) {
      int h0 = s_nb_le[tid + 1] - s_nb_lt[tid];
      int h1 = s_ns_le[tid + 1] - s_ns_lt[tid];
      s_h0[tid] = h0;
      s_h1[tid] = h1;
      s_g0[tid] = h0 > h1;
      s_g1[tid] = h1 > h0;
    }
    __syncthreads();
    if (tid < 64) {
      bool cand = false;
      if (tid + 1 < N_BINS) {
        bool c0 = (s_g0[tid] != s_g0[tid + 1]) && (s_h0[tid] > 0);
        bool c1 = (s_g1[tid] != s_g1[tid + 1]) && (s_h1[tid] > 0);
        cand = c0 || c1;
        if (cand) s_mask[tid + 1] = 1;
      }
      unsigned long long bal = __ballot(cand);
      if (tid == 0 && __popcll(bal) == 1) s_mask[N_BINS] = 1;
    }
    __syncthreads();
    const int Ns = s_ns_le[EDGE_N - 1];
    const int Nb = n - Ns;
    float aC, bC;
    get_ab(aC, bC);
    const float n_f = (float)n;
    float best = INFINITY;
    int bestIdx = 0x7fffffff;
    for (int p = tid; p < EDGE_N * EDGE_N; p += NTHR) {
      int i = p / EDGE_N, j = p - i * EDGE_N;
      float v = INFINITY;
      if (s_mask[i] && s_mask[j] && i < j) {
        int c0 = s_ns_le[i] + (Nb - s_nb_le[i]);
        int c1 = Ns - s_ns_lt[i] + s_nb_lt[i];
        int c2 = s_ns_le[j] - s_ns_lt[i] + Nb - (s_nb_le[j] - s_nb_lt[i]);
        int c3 = s_ns_le[i] + Ns - s_ns_lt[j] + s_nb_le[j] - s_nb_lt[i];
        float L0 = bce_f(c0, n_f, aC, bC);
        float L1 = bce_f(c1, n_f, aC, bC);
        float L2 = bce_f(c2, n_f, aC, bC);
        float L3 = bce_f(c3, n_f, aC, bC);
        v = L0;
        if (L1 < v) v = L1;
        if (L2 < v) v = L2;
        if (L3 < v) v = L3;
      }
      if (v < best || (v == best && p < bestIdx)) { best = v; bestIdx = p; }
    }
    s_rv[tid] = best;
    s_ri[tid] = bestIdx;
    __syncthreads();
    for (int s = NTHR / 2; s > 0; s >>= 1) {
      if (tid < s) {
        float ov = s_rv[tid + s];
        int oi = s_ri[tid + s];
        if (ov < s_rv[tid] || (ov == s_rv[tid] && oi < s_ri[tid])) {
          s_rv[tid] = ov;
          s_ri[tid] = oi;
        }
      }
      __syncthreads();
    }
    if (tid == 0) {
      int p = s_ri[0];
      int i = p / EDGE_N, j = p - i * EDGE_N;
      int c0 = s_ns_le[i] + (Nb - s_nb_le[i]);
      int c1 = Ns - s_ns_lt[i] + s_nb_lt[i];
      int c2 = s_ns_le[j] - s_ns_lt[i] + Nb - (s_nb_le[j] - s_nb_lt[i]);
      int c3 = s_ns_le[i] + Ns - s_ns_lt[j] + s_nb_le[j] - s_nb_lt[i];
      float L0 = bce_f(c0, n_f, aC, bC);
      float L1 = bce_f(c1, n_f, aC, bC);
      float L2 = bce_f(c2, n_f, aC, bC);
      float L3 = bce_f(c3, n_f, aC, bC);
      int cs = 0;
      float m = L0;
      if (L1 < m) { m = L1; cs = 1; }
      if (L2 < m) { m = L2; cs = 2; }
      if (L3 < m) { m = L3; cs = 3; }
      s_cut[0] = cs;
      s_cut[1] = i;
      s_cut[2] = j;
      u32 packed = 0x80000000u | ((u32)cs << 12) | ((u32)i << 6) | (u32)j;
#pragma unroll
      for (int k = 0; k < NREP; ++k) ASTORE(slot(wsu, 5184, k), packed);
    }
    __syncthreads();
  } else {
    if (tid == 0) {
      u32 f;
      while (((f = ALOAD(slot(wsu, 5184, rep))) & 0x80000000u) == 0u)
        __builtin_amdgcn_s_sleep(127);
      s_cut[0] = (int)((f >> 12) & 3u);
      s_cut[1] = (int)((f >> 6) & 63u);
      s_cut[2] = (int)(f & 63u);
    }
    __syncthreads();
  }

  // ---------------- phase D: predict ----------------
  const int cs = s_cut[0], ci = s_cut[1], cj = s_cut[2];
  if (COMPACT) {
    for (int i = gid; i < n; i += T) {
      u32 by = codes[i];  // self-written, cache-hot
      int u = (int)(by & 63u);
      int v = u + (int)(by >> 6);
      bool p0 = (u <= ci), p1 = (ci < v);
      bool p = (cs == 0) ? p0 : (cs == 1) ? p1 : (cs == 2) ? (p1 && (u <= cj)) : (p0 || (cj < v));
      out[i] = p ? 1 : 0;
    }
  } else {
    const float lower = edge_at(ci, xmin, xmax);
    const float upper = edge_at(cj, xmin, xmax);
    for (int i = gid; i < n; i += T) {
      f32x4 r = in4[i];
      KEEP16(r);
      float x = r.x;
      bool p;
      if (cs == 0) p = (x <= lower);
      else if (cs == 1) p = (x >= lower);
      else if (cs == 2) p = (x >= lower) && (x <= upper);
      else p = (x <= lower) || (x >= upper);
      out[i] = p ? 1 : 0;
    }
  }
}

extern "C" void kernel_launch(void* const* d_in, const int* in_sizes, int n_in,
                              void* d_out, int out_size, void* d_ws, size_t ws_size,
                              hipStream_t stream) {
  const f32x4* in4 = (const f32x4*)d_in[0];
  const int* tgt = (const int*)d_in[1];
  int n = in_sizes[1];
  int* out = (int*)d_out;
  char* ws = (char*)d_ws;
  u32* wsu = (u32*)ws;
  int* histU = (int*)(ws + 8192);
  int* histE = (int*)(ws + 14848);
  u8* codes = (u8*)(ws + 24576);
  size_t xcOff = ((size_t)24576 + (size_t)n + 15) & ~(size_t)15;
  float* xc = (float*)(ws + xcOff);
  const bool compact = ws_size >= xcOff + (size_t)n * 4u;

  int maxb = 0;
  hipError_t oe = hipOccupancyMaxActiveBlocksPerMultiprocessor(
      &maxb, compact ? (const void*)k_all<1> : (const void*)k_all<0>, NTHR, 0);
  int nblk = MAXBLK;
  if (oe == hipSuccess && maxb > 0) {
    int cap = maxb * 256;  // 256 CUs on gfx950
    if (cap < nblk) nblk = cap;
  } else {
    nblk = 1024;
  }

  k_init<<<1, NTHR, 0, stream>>>(wsu);
  void* args[10] = {(void*)&in4, (void*)&tgt, (void*)&n, (void*)&nblk, (void*)&wsu,
                    (void*)&histU, (void*)&histE, (void*)&codes, (void*)&xc, (void*)&out};
  if (compact) {
    hipLaunchCooperativeKernel((void*)k_all<1>, dim3(nblk), dim3(NTHR), args, 0, stream);
  } else {
    hipLaunchCooperativeKernel((void*)k_all<0>, dim3(nblk), dim3(NTHR), args, 0, stream);
  }
}

// Round 12
// 110.917 us; speedup vs baseline: 3.7332x; 1.2397x over previous
//
#include <hip/hip_runtime.h>
#include <math.h>
#include <stdint.h>

#define N_BINS 50
#define EDGE_N 51
#define HIST_N 52
#define NTHR 256
#define MAXBLK 1280
#define NREP 16

typedef unsigned int u32;
typedef unsigned short u16;
typedef unsigned char u8;
typedef float f32x4 __attribute__((ext_vector_type(4)));

// ws layout (bytes). Polled words replicated 16x at 64B stride (distinct LLC lines).
// [64   + i*64] cnt1[i]   (barrier-1 arrivals)
// [1088 + i*64] flag1[i]  (barrier-1 release)
// [2112 + i*64] pubMin[i] (enc global min)
// [3136 + i*64] pubMax[i]
// [4160 + i*64] cnt2[i]   (barrier-2 arrivals)
// [5184 + i*64] pub2[i]   (packed cut, bit31 = valid)
// [8192]  int histU[NREP][2*52]
// [14848] int histE[NREP][2*51]
// [21376] u32 bminArr[MAXBLK]  (plain per-block stores, no contention)
// [26496] u32 bmaxArr[MAXBLK]
// [32768] u8 codes[n]              (self-written/self-read per thread)
// [align16 after codes] float xc[n] (self-written/self-read per thread)

#define KEEP16(v) asm volatile("" :: "v"(v))
#define ALOAD(p)     __hip_atomic_load((p), __ATOMIC_RELAXED, __HIP_MEMORY_SCOPE_AGENT)
#define ASTORE(p, v) __hip_atomic_store((p), (v), __ATOMIC_RELAXED, __HIP_MEMORY_SCOPE_AGENT)
#define AADD(p, v)   __hip_atomic_fetch_add((p), (v), __ATOMIC_RELAXED, __HIP_MEMORY_SCOPE_AGENT)
#define VDRAIN() asm volatile("s_waitcnt vmcnt(0)" ::: "memory")

__device__ __forceinline__ u32 f32_enc(float f) {
  u32 u = __float_as_uint(f);
  return (u & 0x80000000u) ? ~u : (u | 0x80000000u);
}
__device__ __forceinline__ float f32_dec(u32 k) {
  u32 u = (k & 0x80000000u) ? (k & 0x7fffffffu) : ~k;
  return __uint_as_float(u);
}
__device__ __forceinline__ u32* slot(u32* wsu, int base_b, int i) {
  return (u32*)((char*)wsu + base_b + i * 64);
}

// jnp.linspace(xmin, xmax, 51) float32 semantics.
__device__ __forceinline__ float edge_at(int e, float xmin, float xmax) {
  if (e >= N_BINS) return xmax;
  float step = __fdiv_rn((float)e, (float)N_BINS);
  float omst = __fsub_rn(1.0f, step);
  return __fadd_rn(__fmul_rn(xmin, omst), __fmul_rn(xmax, step));
}

__device__ __forceinline__ float bce_f(int c, float n_f, float aC, float bC) {
  float cf = (float)c;  // exact, c < 2^24
  float t = __fadd_rn(__fmul_rn(__fsub_rn(n_f, cf), bC), __fmul_rn(cf, aC));
  return __fdiv_rn(t, n_f);
}

__device__ __forceinline__ void get_ab(float& aC, float& bC) {
  const double epsd = (double)1e-7f;
  aC = (float)(-log1p(-epsd));
  bC = (float)(-log(epsd));
}

__global__ void k_init(u32* __restrict__ wsu) {
  // zero control block [0, 8192) + hists [8192, 21376). bmin/bmax need no init
  // (written unconditionally by every block before any read).
  const int t = threadIdx.x;
  for (int i = t; i < 21376 / 4; i += NTHR) wsu[i] = 0u;
}

template <int COMPACT>
__global__ void __launch_bounds__(NTHR, 5)
k_all(const f32x4* __restrict__ in4, const int* __restrict__ tgt, int n, int nblk,
      u32* __restrict__ wsu, int* __restrict__ histU, int* __restrict__ histE,
      u32* __restrict__ bminArr, u32* __restrict__ bmaxArr,
      u8* __restrict__ codes, float* __restrict__ xc, int* __restrict__ out) {
  __shared__ u16 ph[HIST_N][NTHR];  // per-thread private counters, bank-conflict-free
  __shared__ float s_edges[EDGE_N];
  __shared__ int shE[2 * EDGE_N];
  __shared__ float s_red[8];
  __shared__ u32 s_redu[8];
  __shared__ float s_mm[2];
  __shared__ int s_ns_le[EDGE_N], s_ns_lt[EDGE_N], s_nb_le[EDGE_N], s_nb_lt[EDGE_N];
  __shared__ int s_h0[N_BINS], s_h1[N_BINS];
  __shared__ unsigned char s_g0[N_BINS], s_g1[N_BINS];
  __shared__ unsigned char s_mask[EDGE_N];
  __shared__ float s_rv[NTHR];
  __shared__ int s_ri[NTHR];
  __shared__ int s_cut[3];

  const int tid = threadIdx.x, bid = blockIdx.x;
  const int gid = bid * NTHR + tid;
  const int T = nblk * NTHR;
  const int rep = bid & (NREP - 1);

  // zero LDS hist state
  {
    u32* p32 = (u32*)&ph[0][0];
    for (int i = tid; i < HIST_N * (NTHR / 2); i += NTHR) p32[i] = 0;
    for (int i = tid; i < 2 * EDGE_N; i += NTHR) shE[i] = 0;
  }

  // ---------------- phase A: minmax + compact ----------------
  float vmin = INFINITY, vmax = -INFINITY;
  for (int i = gid; i < n; i += T) {
    f32x4 r = in4[i];  // 16 B/lane contiguous row load
    KEEP16(r);
    float x = r.x;
    vmin = fminf(vmin, x);
    vmax = fmaxf(vmax, x);
    if (COMPACT) xc[i] = x;  // self-read in phase B (same thread)
  }
  for (int off = 32; off; off >>= 1) {
    vmin = fminf(vmin, __shfl_down(vmin, off));
    vmax = fmaxf(vmax, __shfl_down(vmax, off));
  }
  {
    int wid = tid >> 6;
    if ((tid & 63) == 0) { s_red[wid] = vmin; s_red[4 + wid] = vmax; }
  }
  __syncthreads();
  // ---- barrier 1: plain per-block stores + replicated arrivals; block-0 reduces ----
  if (tid == 0) {
    float m = s_red[0], M = s_red[4];
    for (int w = 1; w < NTHR / 64; ++w) { m = fminf(m, s_red[w]); M = fmaxf(M, s_red[4 + w]); }
    ASTORE(&bminArr[bid], f32_enc(m));  // zero-contention publication
    ASTORE(&bmaxArr[bid], f32_enc(M));
    VDRAIN();                            // committed at LLC before arrival
    AADD(slot(wsu, 64, rep), 1u);
  }
  if (bid == 0) {
    if (tid == 0) {  // detect: sum 16 arrival lines
      u32 s;
      do {
        s = 0;
#pragma unroll
        for (int k = 0; k < NREP; ++k) s += ALOAD(slot(wsu, 64, k));
        if (s < (u32)nblk) __builtin_amdgcn_s_sleep(8);
      } while (s < (u32)nblk);
    }
    __syncthreads();
    // 256-thread parallel min/max reduce over nblk per-block values
    u32 eMin = 0xFFFFFFFFu, eMax = 0u;
    for (int i = tid; i < nblk; i += NTHR) {
      u32 a = ALOAD(&bminArr[i]);
      u32 b = ALOAD(&bmaxArr[i]);
      eMin = (a < eMin) ? a : eMin;
      eMax = (b > eMax) ? b : eMax;
    }
    for (int off = 32; off; off >>= 1) {
      u32 om = (u32)__shfl_down((int)eMin, off);
      u32 ox = (u32)__shfl_down((int)eMax, off);
      eMin = (om < eMin) ? om : eMin;
      eMax = (ox > eMax) ? ox : eMax;
    }
    {
      int wid = tid >> 6;
      if ((tid & 63) == 0) { s_redu[wid] = eMin; s_redu[4 + wid] = eMax; }
    }
    __syncthreads();
    if (tid == 0) {
      u32 mn = s_redu[0], mx = s_redu[4];
      for (int w = 1; w < NTHR / 64; ++w) {
        mn = (s_redu[w] < mn) ? s_redu[w] : mn;
        mx = (s_redu[4 + w] > mx) ? s_redu[4 + w] : mx;
      }
#pragma unroll
      for (int k = 0; k < NREP; ++k) {
        ASTORE(slot(wsu, 2112, k), mn);
        ASTORE(slot(wsu, 3136, k), mx);
      }
      VDRAIN();  // pub committed before flags
#pragma unroll
      for (int k = 0; k < NREP; ++k) ASTORE(slot(wsu, 1088, k), 1u);
      s_mm[0] = f32_dec(mn);
      s_mm[1] = f32_dec(mx);
    }
  } else {
    if (tid == 0) {
      while (ALOAD(slot(wsu, 1088, rep)) == 0u) __builtin_amdgcn_s_sleep(64);
      s_mm[0] = f32_dec(ALOAD(slot(wsu, 2112, rep)));
      s_mm[1] = f32_dec(ALOAD(slot(wsu, 3136, rep)));
    }
  }
  __syncthreads();

  // ---------------- phase B: histogram + codes ----------------
  const float xmin = s_mm[0], xmax = s_mm[1];
  if (tid < EDGE_N) s_edges[tid] = edge_at(tid, xmin, xmax);
  __syncthreads();
  {
    const float delta = __fdiv_rn(__fsub_rn(xmax, xmin), (float)N_BINS);
    const float inv_delta = (delta > 0.0f) ? (1.0f / delta) : 0.0f;  // guess only
    for (int i = gid; i < n; i += T) {
      float x;
      if (COMPACT) x = xc[i];
      else { f32x4 r = in4[i]; KEEP16(r); x = r.x; }
      int cls = (tgt[i] == 1) ? 0 : 1;
      int g = (int)((x - xmin) * inv_delta);
      g = max(0, min(g, EDGE_N));
      while (g < EDGE_N && s_edges[g] < x) ++g;   // exact: u = #edges < x
      while (g > 0 && s_edges[g - 1] >= x) --g;
      int eq = (g < EDGE_N && s_edges[g] == x) ? 1 : 0;
      ph[g][tid] = (u16)(ph[g][tid] + (1u << (cls * 8)));
      if (eq) atomicAdd(&shE[cls * EDGE_N + g], 1);
      if (COMPACT) codes[i] = (u8)(g | (eq << 6));  // self-read in phase D
    }
    __syncthreads();
    int* hU = histU + rep * (2 * HIST_N);
    int* hE = histE + rep * (2 * EDGE_N);
    if (tid < HIST_N) {  // diagonal stagger over per-thread counters
      const u32* p32 = (const u32*)&ph[0][0];
      u32 c0 = 0, c1 = 0;
      for (int k2 = 0; k2 < NTHR / 2; ++k2) {
        int idx = (k2 + tid) & (NTHR / 2 - 1);
        u32 w = p32[tid * (NTHR / 2) + idx];
        c0 += (w & 0xFFu) + ((w >> 16) & 0xFFu);
        c1 += ((w >> 8) & 0xFFu) + ((w >> 24) & 0xFFu);
      }
      if (c0) atomicAdd(&hU[tid], (int)c0);
      if (c1) atomicAdd(&hU[HIST_N + tid], (int)c1);
    }
    for (int kk = tid; kk < 2 * EDGE_N; kk += NTHR) {
      int v = shE[kk];
      if (v) atomicAdd(&hE[kk], v);
    }
  }
  __syncthreads();
  // ---- barrier 2: arrivals; block 0 decides; packed cut released replicated ----
  if (tid == 0) {
    VDRAIN();  // hist atomics committed before arrival
    AADD(slot(wsu, 4160, rep), 1u);
  }
  if (bid == 0) {
    if (tid == 0) {
      u32 s;
      do {
        s = 0;
#pragma unroll
        for (int k = 0; k < NREP; ++k) s += ALOAD(slot(wsu, 4160, k));
        if (s < (u32)nblk) __builtin_amdgcn_s_sleep(8);
      } while (s < (u32)nblk);
    }
    __syncthreads();
    // ---- decide (verified math; hist reads via atomic loads) ----
    if (tid < 128) {
      const int lane = tid & 63;
      const int w = tid >> 6;  // 0: sig, 1: bkg
      int v = 0;
      if (lane < EDGE_N) {
        for (int r = 0; r < NREP; ++r)
          v += ALOAD((u32*)&histU[r * (2 * HIST_N) + w * HIST_N + lane]);
      }
#pragma unroll
      for (int d = 1; d < 64; d <<= 1) {
        int t = __shfl_up(v, d);
        if (lane >= d) v += t;
      }
      if (lane < EDGE_N) {
        int e = 0;
        for (int r = 0; r < NREP; ++r)
          e += ALOAD((u32*)&histE[r * (2 * EDGE_N) + w * EDGE_N + lane]);
        if (w == 0) { s_ns_le[lane] = v; s_ns_lt[lane] = v - e; }
        else        { s_nb_le[lane] = v; s_nb_lt[lane] = v - e; }
      }
    }
    if (tid < EDGE_N) s_mask[tid] = 0;
    __syncthreads();
    if (tid < N_BINS) {
      int h0 = s_nb_le[tid + 1] - s_nb_lt[tid];
      int h1 = s_ns_le[tid + 1] - s_ns_lt[tid];
      s_h0[tid] = h0;
      s_h1[tid] = h1;
      s_g0[tid] = h0 > h1;
      s_g1[tid] = h1 > h0;
    }
    __syncthreads();
    if (tid < 64) {
      bool cand = false;
      if (tid + 1 < N_BINS) {
        bool c0 = (s_g0[tid] != s_g0[tid + 1]) && (s_h0[tid] > 0);
        bool c1 = (s_g1[tid] != s_g1[tid + 1]) && (s_h1[tid] > 0);
        cand = c0 || c1;
        if (cand) s_mask[tid + 1] = 1;
      }
      unsigned long long bal = __ballot(cand);
      if (tid == 0 && __popcll(bal) == 1) s_mask[N_BINS] = 1;
    }
    __syncthreads();
    const int Ns = s_ns_le[EDGE_N - 1];
    const int Nb = n - Ns;
    float aC, bC;
    get_ab(aC, bC);
    const float n_f = (float)n;
    float best = INFINITY;
    int bestIdx = 0x7fffffff;
    for (int p = tid; p < EDGE_N * EDGE_N; p += NTHR) {
      int i = p / EDGE_N, j = p - i * EDGE_N;
      float v = INFINITY;
      if (s_mask[i] && s_mask[j] && i < j) {
        int c0 = s_ns_le[i] + (Nb - s_nb_le[i]);
        int c1 = Ns - s_ns_lt[i] + s_nb_lt[i];
        int c2 = s_ns_le[j] - s_ns_lt[i] + Nb - (s_nb_le[j] - s_nb_lt[i]);
        int c3 = s_ns_le[i] + Ns - s_ns_lt[j] + s_nb_le[j] - s_nb_lt[i];
        float L0 = bce_f(c0, n_f, aC, bC);
        float L1 = bce_f(c1, n_f, aC, bC);
        float L2 = bce_f(c2, n_f, aC, bC);
        float L3 = bce_f(c3, n_f, aC, bC);
        v = L0;
        if (L1 < v) v = L1;
        if (L2 < v) v = L2;
        if (L3 < v) v = L3;
      }
      if (v < best || (v == best && p < bestIdx)) { best = v; bestIdx = p; }
    }
    s_rv[tid] = best;
    s_ri[tid] = bestIdx;
    __syncthreads();
    for (int s = NTHR / 2; s > 0; s >>= 1) {
      if (tid < s) {
        float ov = s_rv[tid + s];
        int oi = s_ri[tid + s];
        if (ov < s_rv[tid] || (ov == s_rv[tid] && oi < s_ri[tid])) {
          s_rv[tid] = ov;
          s_ri[tid] = oi;
        }
      }
      __syncthreads();
    }
    if (tid == 0) {
      int p = s_ri[0];
      int i = p / EDGE_N, j = p - i * EDGE_N;
      int c0 = s_ns_le[i] + (Nb - s_nb_le[i]);
      int c1 = Ns - s_ns_lt[i] + s_nb_lt[i];
      int c2 = s_ns_le[j] - s_ns_lt[i] + Nb - (s_nb_le[j] - s_nb_lt[i]);
      int c3 = s_ns_le[i] + Ns - s_ns_lt[j] + s_nb_le[j] - s_nb_lt[i];
      float L0 = bce_f(c0, n_f, aC, bC);
      float L1 = bce_f(c1, n_f, aC, bC);
      float L2 = bce_f(c2, n_f, aC, bC);
      float L3 = bce_f(c3, n_f, aC, bC);
      int cs = 0;
      float m = L0;
      if (L1 < m) { m = L1; cs = 1; }
      if (L2 < m) { m = L2; cs = 2; }
      if (L3 < m) { m = L3; cs = 3; }
      s_cut[0] = cs;
      s_cut[1] = i;
      s_cut[2] = j;
      u32 packed = 0x80000000u | ((u32)cs << 12) | ((u32)i << 6) | (u32)j;
#pragma unroll
      for (int k = 0; k < NREP; ++k) ASTORE(slot(wsu, 5184, k), packed);
    }
    __syncthreads();
  } else {
    if (tid == 0) {
      u32 f;
      while (((f = ALOAD(slot(wsu, 5184, rep))) & 0x80000000u) == 0u)
        __builtin_amdgcn_s_sleep(64);
      s_cut[0] = (int)((f >> 12) & 3u);
      s_cut[1] = (int)((f >> 6) & 63u);
      s_cut[2] = (int)(f & 63u);
    }
    __syncthreads();
  }

  // ---------------- phase D: predict ----------------
  const int cs = s_cut[0], ci = s_cut[1], cj = s_cut[2];
  if (COMPACT) {
    for (int i = gid; i < n; i += T) {
      u32 by = codes[i];  // self-written, cache-hot
      int u = (int)(by & 63u);
      int v = u + (int)(by >> 6);
      bool p0 = (u <= ci), p1 = (ci < v);
      bool p = (cs == 0) ? p0 : (cs == 1) ? p1 : (cs == 2) ? (p1 && (u <= cj)) : (p0 || (cj < v));
      out[i] = p ? 1 : 0;
    }
  } else {
    const float lower = edge_at(ci, xmin, xmax);
    const float upper = edge_at(cj, xmin, xmax);
    for (int i = gid; i < n; i += T) {
      f32x4 r = in4[i];
      KEEP16(r);
      float x = r.x;
      bool p;
      if (cs == 0) p = (x <= lower);
      else if (cs == 1) p = (x >= lower);
      else if (cs == 2) p = (x >= lower) && (x <= upper);
      else p = (x <= lower) || (x >= upper);
      out[i] = p ? 1 : 0;
    }
  }
}

extern "C" void kernel_launch(void* const* d_in, const int* in_sizes, int n_in,
                              void* d_out, int out_size, void* d_ws, size_t ws_size,
                              hipStream_t stream) {
  const f32x4* in4 = (const f32x4*)d_in[0];
  const int* tgt = (const int*)d_in[1];
  int n = in_sizes[1];
  int* out = (int*)d_out;
  char* ws = (char*)d_ws;
  u32* wsu = (u32*)ws;
  int* histU = (int*)(ws + 8192);
  int* histE = (int*)(ws + 14848);
  u32* bminArr = (u32*)(ws + 21376);
  u32* bmaxArr = (u32*)(ws + 26496);
  u8* codes = (u8*)(ws + 32768);
  size_t xcOff = ((size_t)32768 + (size_t)n + 15) & ~(size_t)15;
  float* xc = (float*)(ws + xcOff);
  const bool compact = ws_size >= xcOff + (size_t)n * 4u;

  int maxb = 0;
  hipError_t oe = hipOccupancyMaxActiveBlocksPerMultiprocessor(
      &maxb, compact ? (const void*)k_all<1> : (const void*)k_all<0>, NTHR, 0);
  int nblk = MAXBLK;
  if (oe == hipSuccess && maxb > 0) {
    int cap = maxb * 256;  // 256 CUs on gfx950
    if (cap < nblk) nblk = cap;
  } else {
    nblk = 1024;
  }

  k_init<<<1, NTHR, 0, stream>>>(wsu);
  void* args[12] = {(void*)&in4, (void*)&tgt, (void*)&n, (void*)&nblk, (void*)&wsu,
                    (void*)&histU, (void*)&histE, (void*)&bminArr, (void*)&bmaxArr,
                    (void*)&codes, (void*)&xc, (void*)&out};
  if (compact) {
    hipLaunchCooperativeKernel((void*)k_all<1>, dim3(nblk), dim3(NTHR), args, 0, stream);
  } else {
    hipLaunchCooperativeKernel((void*)k_all<0>, dim3(nblk), dim3(NTHR), args, 0, stream);
  }
}

// Round 13
// 87.287 us; speedup vs baseline: 4.7439x; 1.2707x over previous
//
#include <hip/hip_runtime.h>
#include <math.h>
#include <stdint.h>

#define N_BINS 50
#define EDGE_N 51
#define HIST_N 52
#define NTHR 256
#define MAXBLK 2048
#define NREP 16

typedef unsigned int u32;
typedef unsigned short u16;
typedef unsigned char u8;
typedef float f32x4 __attribute__((ext_vector_type(4)));

// ws layout (bytes). Polled words replicated 16x at 64B stride (distinct LLC lines).
// [64   + i*64] cnt1[i]   (barrier-1 arrivals)
// [1088 + i*64] flag1[i]  (barrier-1 release)
// [2112 + i*64] pubMin[i] (enc global min)
// [3136 + i*64] pubMax[i]
// [4160 + i*64] cnt2[i]   (barrier-2 arrivals)
// [5184 + i*64] pub2[i]   (packed cut, bit31 = valid)
// [8192]  int histU[NREP][2*52]
// [14848] int histE[NREP][2*51]
// [21376] u32 bminArr[MAXBLK]  (plain per-block stores, no contention)
// [31616] u32 bmaxArr[MAXBLK]
// [49152] u8 codes[n]              (self-written/self-read per thread)
// [align16 after codes] float xc[n] (self-written/self-read per thread)

#define KEEP16(v) asm volatile("" :: "v"(v))
#define ALOAD(p)     __hip_atomic_load((p), __ATOMIC_RELAXED, __HIP_MEMORY_SCOPE_AGENT)
#define ASTORE(p, v) __hip_atomic_store((p), (v), __ATOMIC_RELAXED, __HIP_MEMORY_SCOPE_AGENT)
#define AADD(p, v)   __hip_atomic_fetch_add((p), (v), __ATOMIC_RELAXED, __HIP_MEMORY_SCOPE_AGENT)
#define VDRAIN() asm volatile("s_waitcnt vmcnt(0)" ::: "memory")

__device__ __forceinline__ u32 f32_enc(float f) {
  u32 u = __float_as_uint(f);
  return (u & 0x80000000u) ? ~u : (u | 0x80000000u);
}
__device__ __forceinline__ float f32_dec(u32 k) {
  u32 u = (k & 0x80000000u) ? (k & 0x7fffffffu) : ~k;
  return __uint_as_float(u);
}
__device__ __forceinline__ u32* slot(u32* wsu, int base_b, int i) {
  return (u32*)((char*)wsu + base_b + i * 64);
}

// jnp.linspace(xmin, xmax, 51) float32 semantics.
__device__ __forceinline__ float edge_at(int e, float xmin, float xmax) {
  if (e >= N_BINS) return xmax;
  float step = __fdiv_rn((float)e, (float)N_BINS);
  float omst = __fsub_rn(1.0f, step);
  return __fadd_rn(__fmul_rn(xmin, omst), __fmul_rn(xmax, step));
}

__device__ __forceinline__ float bce_f(int c, float n_f, float aC, float bC) {
  float cf = (float)c;  // exact, c < 2^24
  float t = __fadd_rn(__fmul_rn(__fsub_rn(n_f, cf), bC), __fmul_rn(cf, aC));
  return __fdiv_rn(t, n_f);
}

__device__ __forceinline__ void get_ab(float& aC, float& bC) {
  const double epsd = (double)1e-7f;
  aC = (float)(-log1p(-epsd));
  bC = (float)(-log(epsd));
}

__global__ void k_init(u32* __restrict__ wsu) {
  // zero control block + hists [0, 21376). bmin/bmax need no init.
  const int t = threadIdx.x;
  for (int i = t; i < 21376 / 4; i += NTHR) wsu[i] = 0u;
}

template <int COMPACT>
__global__ void __launch_bounds__(NTHR, 8)
k_all(const f32x4* __restrict__ in4, const int* __restrict__ tgt, int n, int nblk,
      u32* __restrict__ wsu, int* __restrict__ histU, int* __restrict__ histE,
      u32* __restrict__ bminArr, u32* __restrict__ bmaxArr,
      u8* __restrict__ codes, float* __restrict__ xc, int* __restrict__ out) {
  __shared__ int shU[2 * HIST_N];   // LDS-atomic histogram (416 B -> 8 blocks/CU)
  __shared__ float s_edges[EDGE_N];
  __shared__ int shE[2 * EDGE_N];
  __shared__ float s_red[8];
  __shared__ u32 s_redu[8];
  __shared__ float s_mm[2];
  __shared__ int s_ns_le[EDGE_N], s_ns_lt[EDGE_N], s_nb_le[EDGE_N], s_nb_lt[EDGE_N];
  __shared__ int s_h0[N_BINS], s_h1[N_BINS];
  __shared__ unsigned char s_g0[N_BINS], s_g1[N_BINS];
  __shared__ unsigned char s_mask[EDGE_N];
  __shared__ float s_rv[NTHR];
  __shared__ int s_ri[NTHR];
  __shared__ int s_cut[3];

  const int tid = threadIdx.x, bid = blockIdx.x;
  const int gid = bid * NTHR + tid;
  const int T = nblk * NTHR;
  const int rep = bid & (NREP - 1);

  // zero LDS hist state
  for (int i = tid; i < 2 * HIST_N; i += NTHR) shU[i] = 0;
  for (int i = tid; i < 2 * EDGE_N; i += NTHR) shE[i] = 0;

  // ---------------- phase A: minmax + compact ----------------
  float vmin = INFINITY, vmax = -INFINITY;
#pragma unroll 4
  for (int i = gid; i < n; i += T) {
    f32x4 r = in4[i];  // 16 B/lane contiguous row load
    KEEP16(r);
    float x = r.x;
    vmin = fminf(vmin, x);
    vmax = fmaxf(vmax, x);
    if (COMPACT) xc[i] = x;  // self-read in phase B (same thread)
  }
  for (int off = 32; off; off >>= 1) {
    vmin = fminf(vmin, __shfl_down(vmin, off));
    vmax = fmaxf(vmax, __shfl_down(vmax, off));
  }
  {
    int wid = tid >> 6;
    if ((tid & 63) == 0) { s_red[wid] = vmin; s_red[4 + wid] = vmax; }
  }
  __syncthreads();
  // ---- barrier 1: plain per-block stores + replicated arrivals; block-0 reduces ----
  if (tid == 0) {
    float m = s_red[0], M = s_red[4];
    for (int w = 1; w < NTHR / 64; ++w) { m = fminf(m, s_red[w]); M = fmaxf(M, s_red[4 + w]); }
    ASTORE(&bminArr[bid], f32_enc(m));  // zero-contention publication
    ASTORE(&bmaxArr[bid], f32_enc(M));
    VDRAIN();                            // committed at LLC before arrival
    AADD(slot(wsu, 64, rep), 1u);
  }
  if (bid == 0) {
    if (tid == 0) {  // detect: sum 16 arrival lines
      u32 s;
      do {
        s = 0;
#pragma unroll
        for (int k = 0; k < NREP; ++k) s += ALOAD(slot(wsu, 64, k));
        if (s < (u32)nblk) __builtin_amdgcn_s_sleep(8);
      } while (s < (u32)nblk);
    }
    __syncthreads();
    // 256-thread parallel min/max reduce over nblk per-block values
    u32 eMin = 0xFFFFFFFFu, eMax = 0u;
    for (int i = tid; i < nblk; i += NTHR) {
      u32 a = ALOAD(&bminArr[i]);
      u32 b = ALOAD(&bmaxArr[i]);
      eMin = (a < eMin) ? a : eMin;
      eMax = (b > eMax) ? b : eMax;
    }
    for (int off = 32; off; off >>= 1) {
      u32 om = (u32)__shfl_down((int)eMin, off);
      u32 ox = (u32)__shfl_down((int)eMax, off);
      eMin = (om < eMin) ? om : eMin;
      eMax = (ox > eMax) ? ox : eMax;
    }
    {
      int wid = tid >> 6;
      if ((tid & 63) == 0) { s_redu[wid] = eMin; s_redu[4 + wid] = eMax; }
    }
    __syncthreads();
    if (tid == 0) {
      u32 mn = s_redu[0], mx = s_redu[4];
      for (int w = 1; w < NTHR / 64; ++w) {
        mn = (s_redu[w] < mn) ? s_redu[w] : mn;
        mx = (s_redu[4 + w] > mx) ? s_redu[4 + w] : mx;
      }
#pragma unroll
      for (int k = 0; k < NREP; ++k) {
        ASTORE(slot(wsu, 2112, k), mn);
        ASTORE(slot(wsu, 3136, k), mx);
      }
      VDRAIN();  // pub committed before flags
#pragma unroll
      for (int k = 0; k < NREP; ++k) ASTORE(slot(wsu, 1088, k), 1u);
      s_mm[0] = f32_dec(mn);
      s_mm[1] = f32_dec(mx);
    }
  } else {
    if (tid == 0) {
      while (ALOAD(slot(wsu, 1088, rep)) == 0u) __builtin_amdgcn_s_sleep(64);
      s_mm[0] = f32_dec(ALOAD(slot(wsu, 2112, rep)));
      s_mm[1] = f32_dec(ALOAD(slot(wsu, 3136, rep)));
    }
  }
  __syncthreads();

  // ---------------- phase B: histogram + codes ----------------
  const float xmin = s_mm[0], xmax = s_mm[1];
  if (tid < EDGE_N) s_edges[tid] = edge_at(tid, xmin, xmax);
  __syncthreads();
  {
    const float delta = __fdiv_rn(__fsub_rn(xmax, xmin), (float)N_BINS);
    const float inv_delta = (delta > 0.0f) ? (1.0f / delta) : 0.0f;  // guess only
    for (int i = gid; i < n; i += T) {
      float x;
      if (COMPACT) x = xc[i];
      else { f32x4 r = in4[i]; KEEP16(r); x = r.x; }
      int cls = (tgt[i] == 1) ? 0 : 1;
      int g = (int)((x - xmin) * inv_delta);
      g = max(0, min(g, EDGE_N));
      while (g < EDGE_N && s_edges[g] < x) ++g;   // exact: u = #edges < x
      while (g > 0 && s_edges[g - 1] >= x) --g;
      int eq = (g < EDGE_N && s_edges[g] == x) ? 1 : 0;
      atomicAdd(&shU[cls * HIST_N + g], 1);
      if (eq) atomicAdd(&shE[cls * EDGE_N + g], 1);
      if (COMPACT) codes[i] = (u8)(g | (eq << 6));  // self-read in phase D
    }
    __syncthreads();
    int* hU = histU + rep * (2 * HIST_N);
    int* hE = histE + rep * (2 * EDGE_N);
    for (int kk = tid; kk < 2 * HIST_N; kk += NTHR) {
      int v = shU[kk];
      if (v) atomicAdd(&hU[kk], v);
    }
    for (int kk = tid; kk < 2 * EDGE_N; kk += NTHR) {
      int v = shE[kk];
      if (v) atomicAdd(&hE[kk], v);
    }
  }
  __syncthreads();
  // ---- barrier 2: arrivals; block 0 decides; packed cut released replicated ----
  if (tid == 0) {
    VDRAIN();  // hist atomics committed before arrival
    AADD(slot(wsu, 4160, rep), 1u);
  }
  if (bid == 0) {
    if (tid == 0) {
      u32 s;
      do {
        s = 0;
#pragma unroll
        for (int k = 0; k < NREP; ++k) s += ALOAD(slot(wsu, 4160, k));
        if (s < (u32)nblk) __builtin_amdgcn_s_sleep(8);
      } while (s < (u32)nblk);
    }
    __syncthreads();
    // ---- decide (verified math; hist reads via atomic loads) ----
    if (tid < 128) {
      const int lane = tid & 63;
      const int w = tid >> 6;  // 0: sig, 1: bkg
      int v = 0;
      if (lane < EDGE_N) {
        for (int r = 0; r < NREP; ++r)
          v += ALOAD((u32*)&histU[r * (2 * HIST_N) + w * HIST_N + lane]);
      }
#pragma unroll
      for (int d = 1; d < 64; d <<= 1) {
        int t = __shfl_up(v, d);
        if (lane >= d) v += t;
      }
      if (lane < EDGE_N) {
        int e = 0;
        for (int r = 0; r < NREP; ++r)
          e += ALOAD((u32*)&histE[r * (2 * EDGE_N) + w * EDGE_N + lane]);
        if (w == 0) { s_ns_le[lane] = v; s_ns_lt[lane] = v - e; }
        else        { s_nb_le[lane] = v; s_nb_lt[lane] = v - e; }
      }
    }
    if (tid < EDGE_N) s_mask[tid] = 0;
    __syncthreads();
    if (tid < N_BINS) {
      int h0 = s_nb_le[tid + 1] - s_nb_lt[tid];
      int h1 = s_ns_le[tid + 1] - s_ns_lt[tid];
      s_h0[tid] = h0;
      s_h1[tid] = h1;
      s_g0[tid] = h0 > h1;
      s_g1[tid] = h1 > h0;
    }
    __syncthreads();
    if (tid < 64) {
      bool cand = false;
      if (tid + 1 < N_BINS) {
        bool c0 = (s_g0[tid] != s_g0[tid + 1]) && (s_h0[tid] > 0);
        bool c1 = (s_g1[tid] != s_g1[tid + 1]) && (s_h1[tid] > 0);
        cand = c0 || c1;
        if (cand) s_mask[tid + 1] = 1;
      }
      unsigned long long bal = __ballot(cand);
      if (tid == 0 && __popcll(bal) == 1) s_mask[N_BINS] = 1;
    }
    __syncthreads();
    const int Ns = s_ns_le[EDGE_N - 1];
    const int Nb = n - Ns;
    float aC, bC;
    get_ab(aC, bC);
    const float n_f = (float)n;
    float best = INFINITY;
    int bestIdx = 0x7fffffff;
    for (int p = tid; p < EDGE_N * EDGE_N; p += NTHR) {
      int i = p / EDGE_N, j = p - i * EDGE_N;
      float v = INFINITY;
      if (s_mask[i] && s_mask[j] && i < j) {
        int c0 = s_ns_le[i] + (Nb - s_nb_le[i]);
        int c1 = Ns - s_ns_lt[i] + s_nb_lt[i];
        int c2 = s_ns_le[j] - s_ns_lt[i] + Nb - (s_nb_le[j] - s_nb_lt[i]);
        int c3 = s_ns_le[i] + Ns - s_ns_lt[j] + s_nb_le[j] - s_nb_lt[i];
        float L0 = bce_f(c0, n_f, aC, bC);
        float L1 = bce_f(c1, n_f, aC, bC);
        float L2 = bce_f(c2, n_f, aC, bC);
        float L3 = bce_f(c3, n_f, aC, bC);
        v = L0;
        if (L1 < v) v = L1;
        if (L2 < v) v = L2;
        if (L3 < v) v = L3;
      }
      if (v < best || (v == best && p < bestIdx)) { best = v; bestIdx = p; }
    }
    s_rv[tid] = best;
    s_ri[tid] = bestIdx;
    __syncthreads();
    for (int s = NTHR / 2; s > 0; s >>= 1) {
      if (tid < s) {
        float ov = s_rv[tid + s];
        int oi = s_ri[tid + s];
        if (ov < s_rv[tid] || (ov == s_rv[tid] && oi < s_ri[tid])) {
          s_rv[tid] = ov;
          s_ri[tid] = oi;
        }
      }
      __syncthreads();
    }
    if (tid == 0) {
      int p = s_ri[0];
      int i = p / EDGE_N, j = p - i * EDGE_N;
      int c0 = s_ns_le[i] + (Nb - s_nb_le[i]);
      int c1 = Ns - s_ns_lt[i] + s_nb_lt[i];
      int c2 = s_ns_le[j] - s_ns_lt[i] + Nb - (s_nb_le[j] - s_nb_lt[i]);
      int c3 = s_ns_le[i] + Ns - s_ns_lt[j] + s_nb_le[j] - s_nb_lt[i];
      float L0 = bce_f(c0, n_f, aC, bC);
      float L1 = bce_f(c1, n_f, aC, bC);
      float L2 = bce_f(c2, n_f, aC, bC);
      float L3 = bce_f(c3, n_f, aC, bC);
      int cs = 0;
      float m = L0;
      if (L1 < m) { m = L1; cs = 1; }
      if (L2 < m) { m = L2; cs = 2; }
      if (L3 < m) { m = L3; cs = 3; }
      s_cut[0] = cs;
      s_cut[1] = i;
      s_cut[2] = j;
      u32 packed = 0x80000000u | ((u32)cs << 12) | ((u32)i << 6) | (u32)j;
#pragma unroll
      for (int k = 0; k < NREP; ++k) ASTORE(slot(wsu, 5184, k), packed);
    }
    __syncthreads();
  } else {
    if (tid == 0) {
      u32 f;
      while (((f = ALOAD(slot(wsu, 5184, rep))) & 0x80000000u) == 0u)
        __builtin_amdgcn_s_sleep(64);
      s_cut[0] = (int)((f >> 12) & 3u);
      s_cut[1] = (int)((f >> 6) & 63u);
      s_cut[2] = (int)(f & 63u);
    }
    __syncthreads();
  }

  // ---------------- phase D: predict ----------------
  const int cs = s_cut[0], ci = s_cut[1], cj = s_cut[2];
  if (COMPACT) {
    for (int i = gid; i < n; i += T) {
      u32 by = codes[i];  // self-written, cache-hot
      int u = (int)(by & 63u);
      int v = u + (int)(by >> 6);
      bool p0 = (u <= ci), p1 = (ci < v);
      bool p = (cs == 0) ? p0 : (cs == 1) ? p1 : (cs == 2) ? (p1 && (u <= cj)) : (p0 || (cj < v));
      out[i] = p ? 1 : 0;
    }
  } else {
    const float lower = edge_at(ci, s_mm[0], s_mm[1]);
    const float upper = edge_at(cj, s_mm[0], s_mm[1]);
    for (int i = gid; i < n; i += T) {
      f32x4 r = in4[i];
      KEEP16(r);
      float x = r.x;
      bool p;
      if (cs == 0) p = (x <= lower);
      else if (cs == 1) p = (x >= lower);
      else if (cs == 2) p = (x >= lower) && (x <= upper);
      else p = (x <= lower) || (x >= upper);
      out[i] = p ? 1 : 0;
    }
  }
}

extern "C" void kernel_launch(void* const* d_in, const int* in_sizes, int n_in,
                              void* d_out, int out_size, void* d_ws, size_t ws_size,
                              hipStream_t stream) {
  const f32x4* in4 = (const f32x4*)d_in[0];
  const int* tgt = (const int*)d_in[1];
  int n = in_sizes[1];
  int* out = (int*)d_out;
  char* ws = (char*)d_ws;
  u32* wsu = (u32*)ws;
  int* histU = (int*)(ws + 8192);
  int* histE = (int*)(ws + 14848);
  u32* bminArr = (u32*)(ws + 21376);
  u32* bmaxArr = (u32*)(ws + 31616);
  u8* codes = (u8*)(ws + 49152);
  size_t xcOff = ((size_t)49152 + (size_t)n + 15) & ~(size_t)15;
  float* xc = (float*)(ws + xcOff);
  const bool compact = ws_size >= xcOff + (size_t)n * 4u;

  int maxb = 0;
  hipError_t oe = hipOccupancyMaxActiveBlocksPerMultiprocessor(
      &maxb, compact ? (const void*)k_all<1> : (const void*)k_all<0>, NTHR, 0);
  int nblk = MAXBLK;
  if (oe == hipSuccess && maxb > 0) {
    int cap = maxb * 256;  // 256 CUs on gfx950
    if (cap < nblk) nblk = cap;
  } else {
    nblk = 1024;
  }

  k_init<<<1, NTHR, 0, stream>>>(wsu);
  void* args[12] = {(void*)&in4, (void*)&tgt, (void*)&n, (void*)&nblk, (void*)&wsu,
                    (void*)&histU, (void*)&histE, (void*)&bminArr, (void*)&bmaxArr,
                    (void*)&codes, (void*)&xc, (void*)&out};
  if (compact) {
    hipLaunchCooperativeKernel((void*)k_all<1>, dim3(nblk), dim3(NTHR), args, 0, stream);
  } else {
    hipLaunchCooperativeKernel((void*)k_all<0>, dim3(nblk), dim3(NTHR), args, 0, stream);
  }
}